// Round 17
// baseline (669.038 us; speedup 1.0000x reference)
//
#include <hip/hip_runtime.h>
#include <hip/hip_cooperative_groups.h>
#include <cstdint>
#include <cstddef>

namespace cg = cooperative_groups;

#define NEG_SLOPE 0.2f
#define LOG2E 1.44269504f

typedef __attribute__((ext_vector_type(8))) short short8;   // 8 bf16 (4 VGPRs)
typedef __attribute__((ext_vector_type(4))) float f32x4;    // MFMA accumulator

__device__ __forceinline__ float bf2f(unsigned short u) {
    union { unsigned int i; float f; } x; x.i = ((unsigned int)u) << 16; return x.f;
}
__device__ __forceinline__ unsigned short f2bf(float f) {
    union { float f; unsigned int i; } x;
    x.f = f;
    unsigned int u = x.i;
    return (unsigned short)((u + 0x7FFFu + ((u >> 16) & 1u)) >> 16);   // RNE
}

// 8-lane sum via DPP (VALU pipe, no ds_bpermute): xor1, xor2 quad_perms,
// then row_half_mirror. Group must be 8-lane aligned, uniformly active.
__device__ __forceinline__ float dpp_sum8(float p) {
    p += __int_as_float(__builtin_amdgcn_update_dpp(0, __float_as_int(p), 0xB1, 0xF, 0xF, true));  // quad_perm [1,0,3,2]
    p += __int_as_float(__builtin_amdgcn_update_dpp(0, __float_as_int(p), 0x4E, 0xF, 0xF, true));  // quad_perm [2,3,0,1]
    p += __int_as_float(__builtin_amdgcn_update_dpp(0, __float_as_int(p), 0x141, 0xF, 0xF, true)); // row_half_mirror
    return p;
}

// =====================================================================
// Weight prep (all 3 layers in one launch):
// Bt[n][k] = bf16([Wl | Wr][k][n]); layer0/1: dout=128, layer2: dout=32.
// =====================================================================
__global__ __launch_bounds__(256) void prep_w_all(
    const float* __restrict__ Wl0, const float* __restrict__ Wr0,
    const float* __restrict__ Wl1, const float* __restrict__ Wr1,
    const float* __restrict__ Wl2, const float* __restrict__ Wr2,
    unsigned short* __restrict__ Bt0, unsigned short* __restrict__ Bt1,
    unsigned short* __restrict__ Bt2)
{
    int idx = blockIdx.x * 256 + threadIdx.x;
    const int SZ = 256 * 128;     // layer0/1 table elems
    const float *Wl, *Wr; unsigned short* Bt; int dout;
    if (idx < SZ)              { Wl = Wl0; Wr = Wr0; Bt = Bt0; dout = 128; }
    else if (idx < 2 * SZ)     { Wl = Wl1; Wr = Wr1; Bt = Bt1; dout = 128; idx -= SZ; }
    else if (idx < 2 * SZ + 64 * 128) { Wl = Wl2; Wr = Wr2; Bt = Bt2; dout = 32; idx -= 2 * SZ; }
    else return;
    int n = idx >> 7, k = idx & 127;
    float v = (n < dout) ? Wl[(size_t)k * dout + n] : Wr[(size_t)k * dout + (n - dout)];
    Bt[idx] = f2bf(v);
}

// =====================================================================
// MFMA GEMM (LDS-staged): XL(bf16) | XR(bf16) = A[M x 128] @ Bt^T + b.
// Block = 64 rows x BN cols, 256 threads (4 waves). (r15 config.)
// =====================================================================
template<int BN, bool ABF16>
__global__ __launch_bounds__(256) void gemm_mfma(
    const void* __restrict__ Avoid, int M,
    const unsigned short* __restrict__ Bt,
    const float* __restrict__ bl, const float* __restrict__ br,
    int dout, unsigned short* __restrict__ XL, unsigned short* __restrict__ XR)
{
    constexpr int LDA = 136;                       // shorts; pad 128+8
    constexpr int NT  = BN / 16;
    __shared__ __attribute__((aligned(16))) unsigned short As[64 * LDA];
    __shared__ __attribute__((aligned(16))) unsigned short Bs[BN * LDA];
    const int t  = threadIdx.x;
    const int m0 = blockIdx.x * 64;
    const int n0 = blockIdx.y * BN;

    // ---- stage A (64 x 128 -> bf16 LDS), coalesced
    if (ABF16) {
        const unsigned short* A = (const unsigned short*)Avoid;
#pragma unroll
        for (int i = 0; i < 8; ++i) {
            int c   = t + i * 256;         // ushort4 chunks, [0, 2048)
            int row = c >> 5;              // 32 chunks per row
            int col = (c & 31) * 4;
            int gr  = m0 + row;
            ushort4 v = make_ushort4(0, 0, 0, 0);
            if (gr < M) v = *(const ushort4*)(A + (size_t)gr * 128 + col);
            *(ushort4*)(As + row * LDA + col) = v;
        }
    } else {
        const float* A = (const float*)Avoid;
#pragma unroll
        for (int i = 0; i < 8; ++i) {
            int c   = t + i * 256;         // float4 chunks, [0, 2048)
            int row = c >> 5;
            int col = (c & 31) * 4;
            int gr  = m0 + row;
            float4 v = make_float4(0.f, 0.f, 0.f, 0.f);
            if (gr < M) v = *(const float4*)(A + (size_t)gr * 128 + col);
            ushort4 o;
            o.x = f2bf(v.x); o.y = f2bf(v.y); o.z = f2bf(v.z); o.w = f2bf(v.w);
            *(ushort4*)(As + row * LDA + col) = o;
        }
    }
    // ---- stage B (BN x 128 bf16), coalesced
#pragma unroll
    for (int i = 0; i < BN / 16; ++i) {
        int c  = t + i * 256;              // short8 chunks
        int n  = c >> 4;                   // 16 chunks per row
        int kc = (c & 15) * 8;
        *(short8*)(Bs + n * LDA + kc) =
            *(const short8*)(Bt + (size_t)(n0 + n) * 128 + kc);
    }
    __syncthreads();

    const int w    = t >> 6;
    const int lane = t & 63;
    const int fr   = lane & 15;
    const int quad = lane >> 4;

    f32x4 acc[NT] = {};
    const unsigned short* ap = As + (w * 16 + fr) * LDA + quad * 8;
    const unsigned short* bp = Bs + fr * LDA + quad * 8;
#pragma unroll
    for (int k0 = 0; k0 < 128; k0 += 32) {
        short8 afr = *(const short8*)(ap + k0);
#pragma unroll
        for (int j = 0; j < NT; ++j) {
            short8 bfr = *(const short8*)(bp + j * 16 * LDA + k0);
            acc[j] = __builtin_amdgcn_mfma_f32_16x16x32_bf16(afr, bfr, acc[j], 0, 0, 0);
        }
    }

    // ---- epilogue: +bias, bf16 stores into XL | XR
#pragma unroll
    for (int j = 0; j < NT; ++j) {
        int col = n0 + j * 16 + fr;
        float bias = (col < dout) ? bl[col] : br[col - dout];
#pragma unroll
        for (int r = 0; r < 4; ++r) {
            int row = m0 + w * 16 + quad * 4 + r;
            if (row < M) {
                unsigned short o = f2bf(acc[j][r] + bias);
                if (col < dout) XL[(size_t)row * dout + col] = o;
                else            XR[(size_t)row * dout + (col - dout)] = o;
            }
        }
    }
}

// =====================================================================
// Cooperative CSR build (replaces memset+count+3 scans+place, 6 -> 1):
//   phase 0: zero cnt
//   phase 1: count; per-edge rank captured in REGISTERS (static index)
//   phase 2: hierarchical exclusive scan of cnt -> rowptr
//   phase 3: place csr_src[rowptr[dst]+rank] = src from registers
// Grid = CSR_BLOCKS x 256 (2 blocks/CU -> trivially co-resident).
// =====================================================================
#define CSR_BLOCKS 512
#define CSR_THREADS 256
#define CSR_MAXE 8    // max edges per thread: E <= CSR_MAXE * 512*256 = 1.05M

__global__ __launch_bounds__(CSR_THREADS) void csr_coop(
    const int* __restrict__ src, const int* __restrict__ dst, int E,
    int* __restrict__ cnt, int N,
    int* __restrict__ rowptr, int* __restrict__ bsum,
    unsigned short* __restrict__ csr_src)
{
    cg::grid_group grid = cg::this_grid();
    __shared__ int sh[CSR_BLOCKS];
    const int t   = threadIdx.x;
    const int tid = blockIdx.x * CSR_THREADS + t;
    const int T   = CSR_BLOCKS * CSR_THREADS;

    // ---- phase 0: zero counters
    for (int i = tid; i < N; i += T) cnt[i] = 0;
    grid.sync();

    // ---- phase 1: count + capture (dst, src, rank) in registers
    int ed[CSR_MAXE], es[CSR_MAXE], er[CSR_MAXE];
    bool ok[CSR_MAXE];
#pragma unroll
    for (int j = 0; j < CSR_MAXE; ++j) {
        int e = tid + j * T;
        ok[j] = e < E;
        if (ok[j]) {
            ed[j] = dst[e];
            es[j] = src[e];
            er[j] = atomicAdd(&cnt[ed[j]], 1);
        }
    }
    grid.sync();

    // ---- phase 2a: per-block partial sums of cnt
    const int per = (N + CSR_BLOCKS - 1) / CSR_BLOCKS;
    {
        const int lo = blockIdx.x * per;
        const int hi = min(lo + per, N);
        int s = 0;
        for (int i = lo + t; i < hi; i += CSR_THREADS) s += cnt[i];
#pragma unroll
        for (int off = 32; off >= 1; off >>= 1) s += __shfl_xor(s, off);
        if ((t & 63) == 0) sh[t >> 6] = s;
        __syncthreads();
        if (t == 0) bsum[blockIdx.x] = sh[0] + sh[1] + sh[2] + sh[3];
        __syncthreads();
    }
    grid.sync();

    // ---- phase 2b: block 0 exclusive-scans bsum[CSR_BLOCKS]
    if (blockIdx.x == 0) {
        for (int i = t; i < CSR_BLOCKS; i += CSR_THREADS) sh[i] = bsum[i];
        __syncthreads();
        for (int off = 1; off < CSR_BLOCKS; off <<= 1) {
            int a = (t >= off) ? sh[t - off] : 0;
            int b = (t + CSR_THREADS >= off) ? sh[t + CSR_THREADS - off] : 0;
            __syncthreads();
            sh[t] += a;
            sh[t + CSR_THREADS] += b;
            __syncthreads();
        }
        for (int i = t; i < CSR_BLOCKS; i += CSR_THREADS)
            bsum[i] = sh[i] - bsum[i];           // exclusive prefix
        if (t == 0) rowptr[N] = E;
    }
    grid.sync();

    // ---- phase 2c: per-block chunk scan -> rowptr
    {
        const int lo  = blockIdx.x * per;
        const int len = min(per, N - lo);        // may be <= 0 for tail blocks
        int v = (t < len) ? cnt[lo + t] : 0;     // per <= 256 guaranteed
        sh[t] = v;
        __syncthreads();
        for (int off = 1; off < CSR_THREADS; off <<= 1) {
            int u = (t >= off) ? sh[t - off] : 0;
            __syncthreads();
            sh[t] += u;
            __syncthreads();
        }
        if (t < len) rowptr[lo + t] = bsum[blockIdx.x] + sh[t] - v;
    }
    grid.sync();

    // ---- phase 3: place from registers (no atomics)
#pragma unroll
    for (int j = 0; j < CSR_MAXE; ++j)
        if (ok[j]) csr_src[rowptr[ed[j]] + er[j]] = (unsigned short)es[j];
}

// =====================================================================
// Fused GATv2 edge phase — bf16 xl/xr tables, bf16 output, 4 ch/lane,
// DPP head-reduce (r16-measured-best). Plain-sum exp2-domain softmax.
// One wave per dst node (4 nodes / 256-thread block), no LDS/barriers.
// =====================================================================
template<int H>
__global__ __launch_bounds__(256, 4) void gat_fused(
    const unsigned short* __restrict__ xl, const unsigned short* __restrict__ xr,
    const int* __restrict__ rowptr, const unsigned short* __restrict__ csr_src,
    const float* __restrict__ att, const float* __restrict__ bias,
    unsigned short* __restrict__ hout, int hstride, int N)
{
    constexpr int HC  = 32 * H;
    constexpr int LPE = HC / 4;      // lanes per edge (H=4: 32, H=1: 8)
    constexpr int EPW = 64 / LPE;    // edge slots per wave (2 / 8)
    const int node = blockIdx.x * 4 + (threadIdx.x >> 6);
    if (node >= N) return;
    const int lane = threadIdx.x & 63;
    const int q    = lane % LPE;
    const int slot = lane / LPE;
    const int rs   = rowptr[node];
    const int re   = rowptr[node + 1];

    const unsigned short* __restrict__ xlb = xl + 4 * q;
    float4 xri;
    {
        ushort4 u = *(const ushort4*)(xr + (size_t)node * HC + 4 * q);
        xri.x = bf2f(u.x); xri.y = bf2f(u.y); xri.z = bf2f(u.z); xri.w = bf2f(u.w);
    }
    float4 af = *(const float4*)(att + 4 * q);
    af.x *= LOG2E; af.y *= LOG2E; af.z *= LOG2E; af.w *= LOG2E;   // exp2 domain

    float l = 0.f;
    float4 acc = make_float4(0.f, 0.f, 0.f, 0.f);

    auto ld4 = [&](int s) -> float4 {
        ushort4 u = *(const ushort4*)(xlb + (size_t)s * HC);
        float4 v;
        v.x = bf2f(u.x); v.y = bf2f(u.y); v.z = bf2f(u.z); v.w = bf2f(u.w);
        return v;
    };

    auto edge_w = [&](const float4& v) -> float {   // exp2(att . leakyrelu(v+xri))
        float sx = v.x + xri.x, sy = v.y + xri.y, sz = v.z + xri.z, sw = v.w + xri.w;
        sx = fmaxf(sx, NEG_SLOPE * sx);
        sy = fmaxf(sy, NEG_SLOPE * sy);
        sz = fmaxf(sz, NEG_SLOPE * sz);
        sw = fmaxf(sw, NEG_SLOPE * sw);
        float p = af.x * sx;
        p = fmaf(af.y, sy, p);
        p = fmaf(af.z, sz, p);
        p = fmaf(af.w, sw, p);
        p = dpp_sum8(p);                 // 8-lane head reduce, VALU pipe
        return exp2f(p);
    };

    // ---- self-loop (src = dst = node), slot 0 only
    if (slot == 0) {
        float4 v = ld4(node);
        float w = edge_w(v);
        l = w;
        acc.x = w * v.x; acc.y = w * v.y; acc.z = w * v.z; acc.w = w * v.w;
    }

    // ---- incoming edges, strided per slot, unrolled x2 (no predication)
    int k = rs + slot;
    for (; k + EPW < re; k += 2 * EPW) {
        int s0 = csr_src[k];
        int s1 = csr_src[k + EPW];
        float4 v0 = ld4(s0);
        float4 v1 = ld4(s1);
        float w0 = edge_w(v0);
        float w1 = edge_w(v1);
        l += w0 + w1;
        acc.x = fmaf(w0, v0.x, fmaf(w1, v1.x, acc.x));
        acc.y = fmaf(w0, v0.y, fmaf(w1, v1.y, acc.y));
        acc.z = fmaf(w0, v0.z, fmaf(w1, v1.z, acc.z));
        acc.w = fmaf(w0, v0.w, fmaf(w1, v1.w, acc.w));
    }
    if (k < re) {
        int s0 = csr_src[k];
        float4 v0 = ld4(s0);
        float w0 = edge_w(v0);
        l += w0;
        acc.x = fmaf(w0, v0.x, acc.x);
        acc.y = fmaf(w0, v0.y, acc.y);
        acc.z = fmaf(w0, v0.z, acc.z);
        acc.w = fmaf(w0, v0.w, acc.w);
    }

    // ---- merge edge slots: plain sums (once per node)
#pragma unroll
    for (int mask = LPE; mask < 64; mask <<= 1) {
        l     += __shfl_xor(l, mask);
        acc.x += __shfl_xor(acc.x, mask);
        acc.y += __shfl_xor(acc.y, mask);
        acc.z += __shfl_xor(acc.z, mask);
        acc.w += __shfl_xor(acc.w, mask);
    }

    if (lane < LPE) {
        const float4 bi = *(const float4*)(bias + 4 * q);
        float inv = 1.f / (l + 1e-16f);
        float4 o;
        o.x = acc.x * inv + bi.x;
        o.y = acc.y * inv + bi.y;
        o.z = acc.z * inv + bi.z;
        o.w = acc.w * inv + bi.w;
        o.x = (o.x > 0.f) ? o.x : expm1f(o.x);
        o.y = (o.y > 0.f) ? o.y : expm1f(o.y);
        o.z = (o.z > 0.f) ? o.z : expm1f(o.z);
        o.w = (o.w > 0.f) ? o.w : expm1f(o.w);
        ushort4 ob;
        ob.x = f2bf(o.x); ob.y = f2bf(o.y); ob.z = f2bf(o.z); ob.w = f2bf(o.w);
        *(ushort4*)(hout + (size_t)node * hstride + 4 * q) = ob;
    }
}

// =====================================================================
// Fused mean-pool + MLP head (h is bf16). One block per graph; batch is
// SORTED so graph b's nodes are rows [lower_bound(b), lower_bound(b+1)).
// =====================================================================
__global__ __launch_bounds__(128) void pool_head_kernel(
    const unsigned short* __restrict__ h, int hstride,
    const int* __restrict__ batch, int N,
    const float* __restrict__ meta,
    const float* __restrict__ Wh1, const float* __restrict__ bh1,
    const float* __restrict__ Wh2, const float* __restrict__ bh2,
    float* __restrict__ out)
{
    const int b = blockIdx.x;
    const int t = threadIdx.x;
    __shared__ float s[128];
    __shared__ float z[44];

    int lo = 0, hi = N;
    while (lo < hi) { int mid = (lo + hi) >> 1; if (batch[mid] < b) lo = mid + 1; else hi = mid; }
    int lo2 = lo, hi2 = N;
    while (lo2 < hi2) { int mid = (lo2 + hi2) >> 1; if (batch[mid] < b + 1) lo2 = mid + 1; else hi2 = mid; }
    const int start = lo, end = lo2;

    const int c = t & 31, r = t >> 5;     // 4 rows x 32 channels in flight
    float acc = 0.f;
    for (int row = start + r; row < end; row += 4)
        acc += bf2f(h[(size_t)row * hstride + c]);
    s[t] = acc;
    __syncthreads();
    if (t < 32) {
        float sum = s[t] + s[t + 32] + s[t + 64] + s[t + 96];
        z[t] = sum / fmaxf((float)(end - start), 1.0f);
    } else if (t < 44) {
        z[t] = meta[(size_t)b * 12 + (t - 32)];
    }
    __syncthreads();
    if (t < 32) {
        float hj = bh1[t];
#pragma unroll
        for (int k = 0; k < 44; ++k)
            hj = fmaf(z[k], Wh1[k * 32 + t], hj);
        hj = fmaxf(hj, 0.f);
        float p = hj * Wh2[t];
#pragma unroll
        for (int off = 16; off >= 1; off >>= 1)
            p += __shfl_xor(p, off, 32);
        if (t == 0) out[b] = p + bh2[0];
    }
}

// =====================================================================
extern "C" void kernel_launch(void* const* d_in, const int* in_sizes, int n_in,
                              void* d_out, int out_size, void* d_ws, size_t ws_size,
                              hipStream_t stream)
{
    const float* x     = (const float*)d_in[0];
    const int*   ei    = (const int*)d_in[1];
    const int*   batch = (const int*)d_in[2];
    const float* meta  = (const float*)d_in[3];
    const float* Wl[3]  = {(const float*)d_in[4],  (const float*)d_in[10], (const float*)d_in[16]};
    const float* bl[3]  = {(const float*)d_in[5],  (const float*)d_in[11], (const float*)d_in[17]};
    const float* Wr[3]  = {(const float*)d_in[6],  (const float*)d_in[12], (const float*)d_in[18]};
    const float* br[3]  = {(const float*)d_in[7],  (const float*)d_in[13], (const float*)d_in[19]};
    const float* att[3] = {(const float*)d_in[8],  (const float*)d_in[14], (const float*)d_in[20]};
    const float* bb[3]  = {(const float*)d_in[9],  (const float*)d_in[15], (const float*)d_in[21]};
    const float* Wh1 = (const float*)d_in[22];
    const float* bh1 = (const float*)d_in[23];
    const float* Wh2 = (const float*)d_in[24];
    const float* bh2 = (const float*)d_in[25];
    float* out = (float*)d_out;

    const int N  = in_sizes[0] / 128;
    const int E  = in_sizes[1] / 2;
    const int B  = in_sizes[3] / 12;

    char* wsp = (char*)d_ws;
    size_t off_ = 0;
    auto alloc = [&](size_t bytes) {
        char* p = wsp + off_;
        off_ = (off_ + bytes + 255) & ~(size_t)255;
        return p;
    };
    unsigned short* xlbuf = (unsigned short*)alloc((size_t)N * 128 * 2);  // bf16 gather table
    unsigned short* xrbuf = (unsigned short*)alloc((size_t)N * 128 * 2);  // bf16 xr table
    unsigned short* hbuf  = (unsigned short*)alloc((size_t)N * 128 * 2);  // bf16 layer output
    int*   cnt     = (int*)alloc((size_t)N * 4);
    int*   rowptr  = (int*)alloc((size_t)(N + 1) * 4);
    unsigned short* csr_src = (unsigned short*)alloc((size_t)E * 2);  // src < 65536
    unsigned short* Bt0     = (unsigned short*)alloc((size_t)256 * 128 * 2);
    unsigned short* Bt1     = (unsigned short*)alloc((size_t)256 * 128 * 2);
    unsigned short* Bt2     = (unsigned short*)alloc((size_t)64 * 128 * 2);
    int*   bsum    = (int*)alloc((size_t)CSR_BLOCKS * 4);

    const int* srcI = ei;
    const int* dstI = ei + E;

    // ---- weight prep (independent of everything else)
    prep_w_all<<<(2 * 256 * 128 + 64 * 128 + 255) / 256, 256, 0, stream>>>(
        Wl[0], Wr[0], Wl[1], Wr[1], Wl[2], Wr[2], Bt0, Bt1, Bt2);

    // ---- CSR over dst: single cooperative kernel (zero+count+scan+place)
    {
        void* args[] = {(void*)&srcI, (void*)&dstI, (void*)&E,
                        (void*)&cnt, (void*)&N,
                        (void*)&rowptr, (void*)&bsum, (void*)&csr_src};
        hipLaunchCooperativeKernel((void*)csr_coop, dim3(CSR_BLOCKS),
                                   dim3(CSR_THREADS), args, 0, stream);
    }

    const int GB = (N + 3) / 4;     // gat_fused blocks (4 nodes / 256-thread block)
    const int MB = (N + 63) / 64;   // gemm row-tiles (BM=64)

    // ---- layer 0 (din=128 f32, H=4, C=32, concat)
    {
        gemm_mfma<128, false><<<dim3(MB, 2), 256, 0, stream>>>(x, N, Bt0, bl[0], br[0], 128, xlbuf, xrbuf);
        gat_fused<4><<<GB, 256, 0, stream>>>(xlbuf, xrbuf, rowptr, csr_src, att[0], bb[0], hbuf, 128, N);
    }
    // ---- layer 1 (din=128 bf16)
    {
        gemm_mfma<128, true><<<dim3(MB, 2), 256, 0, stream>>>(hbuf, N, Bt1, bl[1], br[1], 128, xlbuf, xrbuf);
        gat_fused<4><<<GB, 256, 0, stream>>>(xlbuf, xrbuf, rowptr, csr_src, att[1], bb[1], hbuf, 128, N);
    }
    // ---- layer 2 (H=1, concat=False -> mean over 1 head = identity)
    {
        gemm_mfma<64, true><<<dim3(MB, 1), 256, 0, stream>>>(hbuf, N, Bt2, bl[2], br[2], 32, xlbuf, xrbuf);
        gat_fused<1><<<GB, 256, 0, stream>>>(xlbuf, xrbuf, rowptr, csr_src, att[2], bb[2], hbuf, 32, N);
    }
    // ---- fused global mean pool + head (batch sorted -> binary search, no atomics)
    pool_head_kernel<<<B, 128, 0, stream>>>(hbuf, 32, batch, N, meta, Wh1, bh1, Wh2, bh2, out);
}